// Round 11
// baseline (937.619 us; speedup 1.0000x reference)
//
#include <hip/hip_runtime.h>
#include <math.h>

__device__ __forceinline__ float wred_sum(float v){
  #pragma unroll
  for (int o = 32; o > 0; o >>= 1) v += __shfl_xor(v, o);
  return v;
}
__device__ __forceinline__ float wred_max(float v){
  #pragma unroll
  for (int o = 32; o > 0; o >>= 1) v = fmaxf(v, __shfl_xor(v, o));
  return v;
}
__device__ __forceinline__ float lrelu(float v){ return v > 0.f ? v : 0.2f * v; }
__device__ __forceinline__ float sel4(int h, float4 v){
  return (h & 2) ? ((h & 1) ? v.w : v.z) : ((h & 1) ? v.y : v.x);
}

// ---------------- CSR build (dst-sorted) ----------------
__global__ void k_hist(const int* __restrict__ dst, int* __restrict__ deg, int E){
  int t = blockIdx.x * blockDim.x + threadIdx.x;
  if (t < E) atomicAdd(&deg[dst[t]], 1);
}

__global__ void k_deg_bsum(const int* __restrict__ deg, int* __restrict__ bsum, int n){
  __shared__ int s[256];
  int b = blockIdx.x, t = threadIdx.x;
  int i = b * 256 + t;
  s[t] = (i < n) ? deg[i] : 0;
  __syncthreads();
  for (int o = 128; o > 0; o >>= 1){ if (t < o) s[t] += s[t + o]; __syncthreads(); }
  if (t == 0) bsum[b] = s[0];
}
__global__ void k_bsum_scan(int* __restrict__ bsum, int nblk){
  __shared__ int s[256];
  int t = threadIdx.x;
  s[t] = (t < nblk) ? bsum[t] : 0;
  __syncthreads();
  for (int o = 1; o < 256; o <<= 1){
    int add = (t >= o) ? s[t - o] : 0;
    __syncthreads();
    s[t] += add;
    __syncthreads();
  }
  if (t < nblk) bsum[t] = (t > 0) ? s[t - 1] : 0;
}
__global__ void k_rowptr(const int* __restrict__ deg, const int* __restrict__ bsum,
                         int* __restrict__ rowptr, int* __restrict__ cursor, int n, int E){
  __shared__ int s[256];
  int b = blockIdx.x, t = threadIdx.x;
  int i = b * 256 + t;
  int v = (i < n) ? deg[i] : 0;
  s[t] = v;
  __syncthreads();
  for (int o = 1; o < 256; o <<= 1){
    int add = (t >= o) ? s[t - o] : 0;
    __syncthreads();
    s[t] += add;
    __syncthreads();
  }
  if (i < n){
    int rp = bsum[b] + s[t] - v;
    rowptr[i] = rp;
    cursor[i] = rp;
    if (i == n - 1) rowptr[n] = E;
  }
}

__global__ void k_scatter(const int* __restrict__ src, const int* __restrict__ dst,
                          int* __restrict__ cursor, int* __restrict__ esrc, int E){
  int t = blockIdx.x * blockDim.x + threadIdx.x;
  if (t < E){
    int d = dst[t];
    int p = atomicAdd(&cursor[d], 1);
    esrc[p] = src[t];
  }
}

// ---------------- W transpose: W[C][K] -> WT4[k4][c] (float4 over k) ----------------
__global__ void k_wtrans_all(const float* __restrict__ W1a, const float* __restrict__ W1b,
                             const float* __restrict__ W2a, const float* __restrict__ W2b,
                             const float* __restrict__ Wma, const float* __restrict__ Wmb,
                             float4* __restrict__ T1a, float4* __restrict__ T1b,
                             float4* __restrict__ T2a, float4* __restrict__ T2b,
                             float4* __restrict__ Tma, float4* __restrict__ Tmb){
  int idx = blockIdx.x * 256 + threadIdx.x;
  const float* W; float4* T; int C, K4, off;
  if      (idx <  2048){ W = W1a; T = T1a; C = 128; K4 = 16; off = idx; }
  else if (idx <  4096){ W = W1b; T = T1b; C = 128; K4 = 16; off = idx - 2048; }
  else if (idx <  6144){ W = W2a; T = T2a; C =  64; K4 = 32; off = idx - 4096; }
  else if (idx <  8192){ W = W2b; T = T2b; C =  64; K4 = 32; off = idx - 6144; }
  else if (idx < 12288){ W = Wma; T = Tma; C = 256; K4 = 16; off = idx - 8192; }
  else if (idx < 16384){ W = Wmb; T = Tmb; C = 256; K4 = 16; off = idx - 12288; }
  else return;
  int c = off / K4, k4 = off - c * K4;
  const float* p = &W[(size_t)c * (K4 * 4) + 4 * k4];
  T[(size_t)k4 * C + c] = make_float4(p[0], p[1], p[2], p[3]);
}

// ---------------- attention-logit weights, transposed: vvT4[k4][c], c in [0,2H) ----------------
__global__ void k_valvar_all(const float* __restrict__ W1, const float* __restrict__ al1, const float* __restrict__ ar1,
                             const float* __restrict__ W2, const float* __restrict__ al2, const float* __restrict__ ar2,
                             const float* __restrict__ Wm, const float* __restrict__ alm, const float* __restrict__ arm,
                             float* __restrict__ vvT1, float* __restrict__ vvT2, float* __restrict__ vvTm){
  int b = blockIdx.x, k = threadIdx.x;
  if (b == 0){
    if (k < 64){ // L1: K=64, C=128, H=1
      float v = 0.f, w = 0.f;
      for (int c = 0; c < 128; c++){ float ww = W1[c * 64 + k]; v += al1[c] * ww; w += ar1[c] * ww; }
      vvT1[((k >> 2) * 2 + 0) * 4 + (k & 3)] = v;
      vvT1[((k >> 2) * 2 + 1) * 4 + (k & 3)] = w;
    }
  } else if (b == 1){ // L2: K=128, C=64, H=1
    float v = 0.f, w = 0.f;
    for (int c = 0; c < 64; c++){ float ww = W2[c * 128 + k]; v += al2[c] * ww; w += ar2[c] * ww; }
    vvT2[((k >> 2) * 2 + 0) * 4 + (k & 3)] = v;
    vvT2[((k >> 2) * 2 + 1) * 4 + (k & 3)] = w;
  } else {
    if (k < 64){ // MH: K=64, C=256, H=4
      for (int h = 0; h < 4; h++){
        float v = 0.f, w = 0.f;
        for (int c = 0; c < 64; c++){
          float ww = Wm[(size_t)(h * 64 + c) * 64 + k];
          v += alm[h * 64 + c] * ww; w += arm[h * 64 + c] * ww;
        }
        vvTm[((k >> 2) * 8 + 2 * h + 0) * 4 + (k & 3)] = v;
        vvTm[((k >> 2) * 8 + 2 * h + 1) * 4 + (k & 3)] = w;
      }
    }
  }
}

// ---------------- fused dual GEMM, 2 chunk-pairs (4x64 cols) per block ----------------
// blockIdx.y = p < NYC: cols {p*CPB.. } of BOTH Wa and Wb (CPB chunks each);
// p == NYC: logit ext. 16 FMA per XS broadcast read; no launch_bounds (let the
// compiler size VGPR -- r7 showed capping causes spills, r10 showed it sizes right).
template<int K, int C, int H>
__global__ void k_gemm2t(const float* __restrict__ x,
                         const float4* __restrict__ WTa, const float4* __restrict__ WTb,
                         const float4* __restrict__ vvT,
                         float* __restrict__ za, float* __restrict__ zb,
                         float* __restrict__ el, float* __restrict__ er, int n){
  constexpr int K4 = K / 4, NCC = C / 64;
  constexpr int CPB = (NCC >= 2) ? 2 : 1;   // chunks per block (per matrix)
  constexpr int NYC = NCC / CPB;
  constexpr int NM = 2 * CPB;               // acc sets: a-chunks then b-chunks
  constexpr int ROWS = 16384 / (K * 4);
  constexpr int RPW = ROWS / 4;
  __shared__ float XS[ROWS][K];

  int t = threadIdx.x, lane = t & 63, wv = t >> 6;
  int rowbase = blockIdx.x * ROWS;
  int p = blockIdx.y;

  const float4* x4 = (const float4*)x;
  for (int idx = t; idx < ROWS * K4; idx += 256){
    int r = idx / K4, k4 = idx - r * K4;
    int row = rowbase + r;
    float4 v = make_float4(0.f, 0.f, 0.f, 0.f);
    if (row < n) v = x4[(size_t)row * K4 + k4];
    *(float4*)&XS[r][k4 * 4] = v;
  }
  __syncthreads();

  const int r0 = wv * RPW;

  if (p < NYC){
    float acc[NM][RPW];
    #pragma unroll
    for (int m = 0; m < NM; m++)
      #pragma unroll
      for (int r = 0; r < RPW; r++) acc[m][r] = 0.f;

    const float4* Wp[NM];
    #pragma unroll
    for (int cc = 0; cc < CPB; cc++){
      Wp[cc]       = WTa + (size_t)(p * CPB + cc) * 64 + lane;
      Wp[CPB + cc] = WTb + (size_t)(p * CPB + cc) * 64 + lane;
    }

    #pragma unroll 2
    for (int k4 = 0; k4 < K4; k4++){
      float4 w[NM];
      #pragma unroll
      for (int m = 0; m < NM; m++) w[m] = Wp[m][(size_t)k4 * C];
      #pragma unroll
      for (int r = 0; r < RPW; r++){
        float4 xk = *(const float4*)&XS[r0 + r][k4 * 4];
        #pragma unroll
        for (int m = 0; m < NM; m++){
          acc[m][r] += xk.x * w[m].x + xk.y * w[m].y + xk.z * w[m].z + xk.w * w[m].w;
        }
      }
    }

    #pragma unroll
    for (int r = 0; r < RPW; r++){
      int row = rowbase + r0 + r;
      if (row < n){
        #pragma unroll
        for (int cc = 0; cc < CPB; cc++){
          za[(size_t)row * C + (p * CPB + cc) * 64 + lane] = acc[cc][r];
          zb[(size_t)row * C + (p * CPB + cc) * 64 + lane] = acc[CPB + cc][r];
        }
      }
    }
  } else if (lane < 2 * H){
    // ext: el/er from vvT (cols 0..2H-1)
    float acc0[RPW];
    #pragma unroll
    for (int r = 0; r < RPW; r++) acc0[r] = 0.f;
    for (int k4 = 0; k4 < K4; k4++){
      float4 w0 = vvT[(size_t)k4 * (2 * H) + lane];
      #pragma unroll
      for (int r = 0; r < RPW; r++){
        float4 xk = *(const float4*)&XS[r0 + r][k4 * 4];
        acc0[r] += xk.x * w0.x + xk.y * w0.y + xk.z * w0.z + xk.w * w0.w;
      }
    }
    int h = lane >> 1;
    float* dst = (lane & 1) ? er : el;
    #pragma unroll
    for (int r = 0; r < RPW; r++){
      int row = rowbase + r0 + r;
      if (row < n) dst[(size_t)row * H + h] = acc0[r];
    }
  }
}

// ---------------- GAT 1-head, float4 gather, NS edges/iter in lane-slots ----------------
template<int D>
__global__ void k_gat_h1(const int* __restrict__ rowptr, const int* __restrict__ esrc,
                         const float* __restrict__ z, const float* __restrict__ el,
                         const float* __restrict__ er, const float* __restrict__ b,
                         const float* __restrict__ zb, const float* __restrict__ bb,
                         float* __restrict__ out, int n){
  constexpr int LPS = D / 4;
  constexpr int NS  = 64 / LPS;
  int lane = threadIdx.x & 63;
  int q = lane / LPS, j = lane % LPS;
  int i = blockIdx.x * (blockDim.x >> 6) + (threadIdx.x >> 6);
  if (i >= n) return;
  int s0 = rowptr[i], s1 = rowptr[i + 1];
  float eri = er[i];
  float m = -INFINITY;
  for (int e = s0 + lane; e < s1; e += 64)
    m = fmaxf(m, lrelu(el[esrc[e]] + eri));
  m = wred_max(m);
  float4 acc = make_float4(0.f, 0.f, 0.f, 0.f);
  float den = 0.f;
  for (int base = s0; base < s1; base += NS){
    int e = base + q;
    bool ok = (e < s1);
    int s = esrc[ok ? e : s0];
    float w = ok ? __expf(lrelu(el[s] + eri) - m) : 0.f;
    den += w;
    float4 zv = *(const float4*)&z[(size_t)s * D + 4 * j];
    acc.x += w * zv.x; acc.y += w * zv.y; acc.z += w * zv.z; acc.w += w * zv.w;
  }
  #pragma unroll
  for (int o = LPS; o < 64; o <<= 1){
    acc.x += __shfl_xor(acc.x, o);
    acc.y += __shfl_xor(acc.y, o);
    acc.z += __shfl_xor(acc.z, o);
    acc.w += __shfl_xor(acc.w, o);
    den   += __shfl_xor(den, o);
  }
  float inv = (s1 > s0) ? 1.f / den : 0.f;
  if (lane < LPS){
    float4 bv  = *(const float4*)&b[4 * j];
    float4 ch  = *(const float4*)&bb[4 * j];
    if (i > 0){
      float4 zbv = *(const float4*)&zb[(size_t)(i - 1) * D + 4 * j];
      ch.x += zbv.x; ch.y += zbv.y; ch.z += zbv.z; ch.w += zbv.w;
    }
    float4 o4;
    o4.x = 0.5f * ((acc.x * inv + bv.x) + ch.x);
    o4.y = 0.5f * ((acc.y * inv + bv.y) + ch.y);
    o4.z = 0.5f * ((acc.z * inv + bv.z) + ch.z);
    o4.w = 0.5f * ((acc.w * inv + bv.w) + ch.w);
    *(float4*)&out[(size_t)i * D + 4 * j] = o4;
  }
}

// ---------------- GAT 4-head, float4 gather ----------------
__global__ void k_gat_mh(const int* __restrict__ rowptr, const int* __restrict__ esrc,
                         const float* __restrict__ z, const float* __restrict__ el,
                         const float* __restrict__ er, const float* __restrict__ b,
                         const float* __restrict__ zb, const float* __restrict__ bb,
                         float* __restrict__ out, int n){
  int lane = threadIdx.x & 63;
  int h = lane >> 4;
  int i = blockIdx.x * (blockDim.x >> 6) + (threadIdx.x >> 6);
  if (i >= n) return;
  int s0 = rowptr[i], s1 = rowptr[i + 1];
  const float4 eri4 = *(const float4*)(er + (size_t)i * 4);
  float m0 = -INFINITY, m1 = -INFINITY, m2 = -INFINITY, m3 = -INFINITY;
  for (int e = s0 + lane; e < s1; e += 64){
    float4 e4 = *(const float4*)(el + (size_t)esrc[e] * 4);
    m0 = fmaxf(m0, lrelu(e4.x + eri4.x));
    m1 = fmaxf(m1, lrelu(e4.y + eri4.y));
    m2 = fmaxf(m2, lrelu(e4.z + eri4.z));
    m3 = fmaxf(m3, lrelu(e4.w + eri4.w));
  }
  m0 = wred_max(m0); m1 = wred_max(m1); m2 = wred_max(m2); m3 = wred_max(m3);
  float msel = (h & 2) ? ((h & 1) ? m3 : m2) : ((h & 1) ? m1 : m0);
  float erh  = sel4(h, eri4);

  float4 acc  = make_float4(0.f, 0.f, 0.f, 0.f);
  float4 accB = make_float4(0.f, 0.f, 0.f, 0.f);
  float den = 0.f, denB = 0.f;
  int e = s0;
  for (; e + 1 < s1; e += 2){
    int sA = esrc[e], sB = esrc[e + 1];
    float4 eA = *(const float4*)(el + (size_t)sA * 4);
    float4 eB = *(const float4*)(el + (size_t)sB * 4);
    float wA = __expf(lrelu(sel4(h, eA) + erh) - msel);
    float wB = __expf(lrelu(sel4(h, eB) + erh) - msel);
    den += wA; denB += wB;
    float4 zA = *(const float4*)&z[(size_t)sA * 256 + 4 * lane];
    float4 zB = *(const float4*)&z[(size_t)sB * 256 + 4 * lane];
    acc.x  += wA * zA.x; acc.y  += wA * zA.y; acc.z  += wA * zA.z; acc.w  += wA * zA.w;
    accB.x += wB * zB.x; accB.y += wB * zB.y; accB.z += wB * zB.z; accB.w += wB * zB.w;
  }
  if (e < s1){
    int sA = esrc[e];
    float4 eA = *(const float4*)(el + (size_t)sA * 4);
    float wA = __expf(lrelu(sel4(h, eA) + erh) - msel);
    den += wA;
    float4 zA = *(const float4*)&z[(size_t)sA * 256 + 4 * lane];
    acc.x += wA * zA.x; acc.y += wA * zA.y; acc.z += wA * zA.z; acc.w += wA * zA.w;
  }
  den += denB;
  acc.x += accB.x; acc.y += accB.y; acc.z += accB.z; acc.w += accB.w;
  float inv = (s1 > s0) ? 1.f / den : 0.f;

  float4 bv = *(const float4*)&b[4 * lane];
  float4 ch = *(const float4*)&bb[4 * lane];
  if (i > 0){
    float4 zbv = *(const float4*)&zb[(size_t)(i - 1) * 256 + 4 * lane];
    ch.x += zbv.x; ch.y += zbv.y; ch.z += zbv.z; ch.w += zbv.w;
  }
  float4 o4;
  o4.x = 0.5f * ((acc.x * inv + bv.x) + ch.x);
  o4.y = 0.5f * ((acc.y * inv + bv.y) + ch.y);
  o4.z = 0.5f * ((acc.z * inv + bv.z) + ch.z);
  o4.w = 0.5f * ((acc.w * inv + bv.w) + ch.w);
  *(float4*)&out[(size_t)i * 256 + 4 * lane] = o4;
}

// ---------------- chain_pass ----------------
__global__ void k_chainpass64(const float* __restrict__ h, float* __restrict__ dh, int n){
  int lane = threadIdx.x & 63;
  int i = blockIdx.x * (blockDim.x >> 6) + (threadIdx.x >> 6);
  if (i >= n) return;
  float d = 0.f;
  if (i > 0) d = h[(size_t)(i - 1) * 64 + lane] - h[(size_t)i * 64 + lane];
  float ss = wred_sum(d * d);
  dh[(size_t)i * 64 + lane] = d / (sqrtf(ss) + 1e-7f);
}

__global__ void k_chainpass_mh(const float* __restrict__ hm, float* __restrict__ ds, int n){
  int lane = threadIdx.x & 63;
  int i = blockIdx.x * (blockDim.x >> 6) + (threadIdx.x >> 6);
  if (i >= n) return;
  const float* cur = hm + (size_t)i * 256;
  const float* prv = hm + (size_t)(i - 1) * 256;
  #pragma unroll
  for (int h = 0; h < 4; h++){
    int c = h * 64 + lane;
    float d = (i > 0) ? (prv[c] - cur[c]) : 0.f;
    float ss = wred_sum(d * d);
    ds[(size_t)i * 256 + c] = d / (sqrtf(ss) + 1e-7f);
  }
}

// ---------------- column-wise prefix sum over nodes (256 cols) ----------------
__global__ void k_chunk_sum(const float* __restrict__ ds, float* __restrict__ csum, int n, int ch){
  int b = blockIdx.x, t = threadIdx.x;
  int r0 = b * ch, r1 = r0 + ch; if (r1 > n) r1 = n;
  float s = 0.f;
  for (int r = r0; r < r1; r++) s += ds[(size_t)r * 256 + t];
  csum[(size_t)b * 256 + t] = s;
}
__global__ void k_scan_chunks_par(float* __restrict__ csum, int nb){
  __shared__ float s[512];
  int col = blockIdx.x;
  int t = threadIdx.x;
  s[t] = (t < nb) ? csum[(size_t)t * 256 + col] : 0.f;
  __syncthreads();
  #pragma unroll
  for (int o = 1; o < 512; o <<= 1){
    float add = (t >= o) ? s[t - o] : 0.f;
    __syncthreads();
    s[t] += add;
    __syncthreads();
  }
  if (t < nb) csum[(size_t)t * 256 + col] = (t > 0) ? s[t - 1] : 0.f;
}
__global__ void k_apply_scan(float* __restrict__ ds, const float* __restrict__ csum, int n, int ch){
  int b = blockIdx.x, t = threadIdx.x;
  int r0 = b * ch, r1 = r0 + ch; if (r1 > n) r1 = n;
  float run = csum[(size_t)b * 256 + t];
  for (int r = r0; r < r1; r++){
    run += ds[(size_t)r * 256 + t];
    ds[(size_t)r * 256 + t] = run;
  }
}

extern "C" void kernel_launch(void* const* d_in, const int* in_sizes, int n_in,
                              void* d_out, int out_size, void* d_ws, size_t ws_size,
                              hipStream_t stream){
  const float* x    = (const float*)d_in[0];
  const int*   src0 = (const int*)d_in[1];
  const int*   dst0 = (const int*)d_in[2];
  const float* W1a  = (const float*)d_in[5];
  const float* al1a = (const float*)d_in[6];
  const float* ar1a = (const float*)d_in[7];
  const float* b1a  = (const float*)d_in[8];
  const float* W1b  = (const float*)d_in[9];
  const float* b1b  = (const float*)d_in[12];
  const float* W2a  = (const float*)d_in[13];
  const float* al2a = (const float*)d_in[14];
  const float* ar2a = (const float*)d_in[15];
  const float* b2a  = (const float*)d_in[16];
  const float* W2b  = (const float*)d_in[17];
  const float* b2b  = (const float*)d_in[20];
  const float* Wma  = (const float*)d_in[21];
  const float* alma = (const float*)d_in[22];
  const float* arma = (const float*)d_in[23];
  const float* bma  = (const float*)d_in[24];
  const float* Wmb  = (const float*)d_in[25];
  const float* bmb  = (const float*)d_in[28];

  const int n = in_sizes[0] / 64;
  const int E = in_sizes[1];
  const size_t nf = (size_t)n;

  float* ws  = (float*)d_ws;
  float* A   = ws;
  float* B   = A + nf * 256;
  float* C   = B + nf * 256;
  float* D2  = C + nf * 256;   // h2 [n,64]
  float* E2  = D2 + nf * 64;   // dh [n,64]
  float* ela = E2 + nf * 64;   // [n,4]
  float* era = ela + nf * 4;
  const int ch = 100;
  const int nb = (n + ch - 1) / ch;      // 500 <= 512
  float* csum = era + nf * 4;  // [nb,256]
  float* wtbase = csum + (size_t)nb * 256;
  float4* T1a = (float4*)wtbase;          // [16][128] f4 = 2048
  float4* T1b = T1a + 2048;
  float4* T2a = T1b + 2048;               // [32][64]  f4 = 2048
  float4* T2b = T2a + 2048;
  float4* Tma = T2b + 2048;               // [16][256] f4 = 4096
  float4* Tmb = Tma + 4096;
  float* vvT1 = (float*)(Tmb + 4096);     // [16][2] f4 -> 128 floats
  float* vvT2 = vvT1 + 128;               // [32][2] f4 -> 256 floats
  float* vvTm = vvT2 + 256;               // [16][8] f4 -> 512 floats
  int* deg    = (int*)(vvTm + 512);
  int* rowptr = deg + n;
  int* cursor = rowptr + (n + 16);
  int* esrc   = cursor + n;
  int* bsum   = esrc + E;

  float* dsout = (float*)d_out;

  const int nwb  = (n + 3) / 4;
  const int eb   = (E + 255) / 256;
  const int nblk = (n + 255) / 256;

  // CSR of interacts graph by dst (shared by all three GAT layers)
  hipMemsetAsync(deg, 0, (size_t)n * sizeof(int), stream);
  k_hist<<<eb, 256, 0, stream>>>(dst0, deg, E);
  k_deg_bsum<<<nblk, 256, 0, stream>>>(deg, bsum, n);
  k_bsum_scan<<<1, 256, 0, stream>>>(bsum, nblk);
  k_rowptr<<<nblk, 256, 0, stream>>>(deg, bsum, rowptr, cursor, n, E);
  k_scatter<<<eb, 256, 0, stream>>>(src0, dst0, cursor, esrc, E);

  // weight preprocessing
  k_wtrans_all<<<64, 256, 0, stream>>>(W1a, W1b, W2a, W2b, Wma, Wmb,
                                       T1a, T1b, T2a, T2b, Tma, Tmb);
  k_valvar_all<<<3, 128, 0, stream>>>(W1a, al1a, ar1a, W2a, al2a, ar2a, Wma, alma, arma,
                                      vvT1, vvT2, vvTm);

  // layer 1: in=64 -> hid=128 (a+b fused; grid.y = {chunk-pair 0, ext})
  k_gemm2t<64, 128, 1><<<dim3((n + 63) / 64, 2), 256, 0, stream>>>(x, T1a, T1b, (const float4*)vvT1, A, B, ela, era, n);
  k_gat_h1<128><<<nwb, 256, 0, stream>>>(rowptr, esrc, A, ela, era, b1a, B, b1b, C, n);

  // layer 2: hid=128 -> out=64 (grid.y = {chunk 0, ext})
  k_gemm2t<128, 64, 1><<<dim3((n + 31) / 32, 2), 256, 0, stream>>>(C, T2a, T2b, (const float4*)vvT2, A, B, ela, era, n);
  k_gat_h1<64><<<nwb, 256, 0, stream>>>(rowptr, esrc, A, ela, era, b2a, B, b2b, D2, n);

  // dh = chain_pass(h2)
  k_chainpass64<<<nwb, 256, 0, stream>>>(D2, E2, n);

  // MH layer: out=64 -> 4 heads x 64 (grid.y = {pair0, pair1, ext})
  k_gemm2t<64, 256, 4><<<dim3((n + 63) / 64, 3), 256, 0, stream>>>(E2, Tma, Tmb, (const float4*)vvTm, A, B, ela, era, n);
  k_gat_mh<<<nwb, 256, 0, stream>>>(rowptr, esrc, A, ela, era, bma, B, bmb, C, n);

  // ds = chain_pass(hm) -> staged directly in d_out
  k_chainpass_mh<<<nwb, 256, 0, stream>>>(C, dsout, n);

  // res = cumsum(ds, axis=0), in-place in d_out
  k_chunk_sum<<<nb, 256, 0, stream>>>(dsout, csum, n, ch);
  k_scan_chunks_par<<<256, 512, 0, stream>>>(csum, nb);
  k_apply_scan<<<nb, 256, 0, stream>>>(dsout, csum, n, ch);
}

// Round 12
// 628.239 us; speedup vs baseline: 1.4925x; 1.4925x over previous
//
#include <hip/hip_runtime.h>
#include <math.h>

__device__ __forceinline__ float wred_sum(float v){
  #pragma unroll
  for (int o = 32; o > 0; o >>= 1) v += __shfl_xor(v, o);
  return v;
}
__device__ __forceinline__ float wred_max(float v){
  #pragma unroll
  for (int o = 32; o > 0; o >>= 1) v = fmaxf(v, __shfl_xor(v, o));
  return v;
}
__device__ __forceinline__ float lrelu(float v){ return v > 0.f ? v : 0.2f * v; }
__device__ __forceinline__ float sel4(int h, float4 v){
  return (h & 2) ? ((h & 1) ? v.w : v.z) : ((h & 1) ? v.y : v.x);
}

// ---------------- CSR build (dst-sorted) ----------------
__global__ void k_hist(const int* __restrict__ dst, int* __restrict__ deg, int E){
  int t = blockIdx.x * blockDim.x + threadIdx.x;
  if (t < E) atomicAdd(&deg[dst[t]], 1);
}

__global__ void k_deg_bsum(const int* __restrict__ deg, int* __restrict__ bsum, int n){
  __shared__ int s[256];
  int b = blockIdx.x, t = threadIdx.x;
  int i = b * 256 + t;
  s[t] = (i < n) ? deg[i] : 0;
  __syncthreads();
  for (int o = 128; o > 0; o >>= 1){ if (t < o) s[t] += s[t + o]; __syncthreads(); }
  if (t == 0) bsum[b] = s[0];
}
__global__ void k_bsum_scan(int* __restrict__ bsum, int nblk){
  __shared__ int s[256];
  int t = threadIdx.x;
  s[t] = (t < nblk) ? bsum[t] : 0;
  __syncthreads();
  for (int o = 1; o < 256; o <<= 1){
    int add = (t >= o) ? s[t - o] : 0;
    __syncthreads();
    s[t] += add;
    __syncthreads();
  }
  if (t < nblk) bsum[t] = (t > 0) ? s[t - 1] : 0;
}
__global__ void k_rowptr(const int* __restrict__ deg, const int* __restrict__ bsum,
                         int* __restrict__ rowptr, int* __restrict__ cursor, int n, int E){
  __shared__ int s[256];
  int b = blockIdx.x, t = threadIdx.x;
  int i = b * 256 + t;
  int v = (i < n) ? deg[i] : 0;
  s[t] = v;
  __syncthreads();
  for (int o = 1; o < 256; o <<= 1){
    int add = (t >= o) ? s[t - o] : 0;
    __syncthreads();
    s[t] += add;
    __syncthreads();
  }
  if (i < n){
    int rp = bsum[b] + s[t] - v;
    rowptr[i] = rp;
    cursor[i] = rp;
    if (i == n - 1) rowptr[n] = E;
  }
}

__global__ void k_scatter(const int* __restrict__ src, const int* __restrict__ dst,
                          int* __restrict__ cursor, int* __restrict__ esrc, int E){
  int t = blockIdx.x * blockDim.x + threadIdx.x;
  if (t < E){
    int d = dst[t];
    int p = atomicAdd(&cursor[d], 1);
    esrc[p] = src[t];
  }
}

// ---------------- W transpose: W[C][K] -> WT4[k4][c] (float4 over k) ----------------
__global__ void k_wtrans_all(const float* __restrict__ W1a, const float* __restrict__ W1b,
                             const float* __restrict__ W2a, const float* __restrict__ W2b,
                             const float* __restrict__ Wma, const float* __restrict__ Wmb,
                             float4* __restrict__ T1a, float4* __restrict__ T1b,
                             float4* __restrict__ T2a, float4* __restrict__ T2b,
                             float4* __restrict__ Tma, float4* __restrict__ Tmb){
  int idx = blockIdx.x * 256 + threadIdx.x;
  const float* W; float4* T; int C, K4, off;
  if      (idx <  2048){ W = W1a; T = T1a; C = 128; K4 = 16; off = idx; }
  else if (idx <  4096){ W = W1b; T = T1b; C = 128; K4 = 16; off = idx - 2048; }
  else if (idx <  6144){ W = W2a; T = T2a; C =  64; K4 = 32; off = idx - 4096; }
  else if (idx <  8192){ W = W2b; T = T2b; C =  64; K4 = 32; off = idx - 6144; }
  else if (idx < 12288){ W = Wma; T = Tma; C = 256; K4 = 16; off = idx - 8192; }
  else if (idx < 16384){ W = Wmb; T = Tmb; C = 256; K4 = 16; off = idx - 12288; }
  else return;
  int c = off / K4, k4 = off - c * K4;
  const float* p = &W[(size_t)c * (K4 * 4) + 4 * k4];
  T[(size_t)k4 * C + c] = make_float4(p[0], p[1], p[2], p[3]);
}

// ---------------- attention-logit weights, transposed: vvT4[k4][c], c in [0,2H) ----------------
__global__ void k_valvar_all(const float* __restrict__ W1, const float* __restrict__ al1, const float* __restrict__ ar1,
                             const float* __restrict__ W2, const float* __restrict__ al2, const float* __restrict__ ar2,
                             const float* __restrict__ Wm, const float* __restrict__ alm, const float* __restrict__ arm,
                             float* __restrict__ vvT1, float* __restrict__ vvT2, float* __restrict__ vvTm){
  int b = blockIdx.x, k = threadIdx.x;
  if (b == 0){
    if (k < 64){ // L1: K=64, C=128, H=1
      float v = 0.f, w = 0.f;
      for (int c = 0; c < 128; c++){ float ww = W1[c * 64 + k]; v += al1[c] * ww; w += ar1[c] * ww; }
      vvT1[((k >> 2) * 2 + 0) * 4 + (k & 3)] = v;
      vvT1[((k >> 2) * 2 + 1) * 4 + (k & 3)] = w;
    }
  } else if (b == 1){ // L2: K=128, C=64, H=1
    float v = 0.f, w = 0.f;
    for (int c = 0; c < 64; c++){ float ww = W2[c * 128 + k]; v += al2[c] * ww; w += ar2[c] * ww; }
    vvT2[((k >> 2) * 2 + 0) * 4 + (k & 3)] = v;
    vvT2[((k >> 2) * 2 + 1) * 4 + (k & 3)] = w;
  } else {
    if (k < 64){ // MH: K=64, C=256, H=4
      for (int h = 0; h < 4; h++){
        float v = 0.f, w = 0.f;
        for (int c = 0; c < 64; c++){
          float ww = Wm[(size_t)(h * 64 + c) * 64 + k];
          v += alm[h * 64 + c] * ww; w += arm[h * 64 + c] * ww;
        }
        vvTm[((k >> 2) * 8 + 2 * h + 0) * 4 + (k & 3)] = v;
        vvTm[((k >> 2) * 8 + 2 * h + 1) * 4 + (k & 3)] = w;
      }
    }
  }
}

// ---------------- fused dual GEMM (r10 body, measured 89us MH, VGPR 40) ----------------
// blockIdx.y = p: p < NCC -> 64-col chunk p of both Wa and Wb; p == NCC -> logit ext.
// NOTE: do NOT widen to 4 acc sets or add launch_bounds -- compiler pins VGPR=64
// for this shape and spills (r7: 84+spill, r11: 64+1.1GB scratch traffic).
template<int K, int C, int H>
__global__ void k_gemm2t(const float* __restrict__ x,
                         const float4* __restrict__ WTa, const float4* __restrict__ WTb,
                         const float4* __restrict__ vvT,
                         float* __restrict__ za, float* __restrict__ zb,
                         float* __restrict__ el, float* __restrict__ er, int n){
  constexpr int K4 = K / 4, NCC = C / 64;
  constexpr int ROWS = 16384 / (K * 4);
  constexpr int RPW = ROWS / 4;
  __shared__ float XS[ROWS][K];

  int t = threadIdx.x, lane = t & 63, wv = t >> 6;
  int rowbase = blockIdx.x * ROWS;
  int p = blockIdx.y;

  const float4* x4 = (const float4*)x;
  for (int idx = t; idx < ROWS * K4; idx += 256){
    int r = idx / K4, k4 = idx - r * K4;
    int row = rowbase + r;
    float4 v = make_float4(0.f, 0.f, 0.f, 0.f);
    if (row < n) v = x4[(size_t)row * K4 + k4];
    *(float4*)&XS[r][k4 * 4] = v;
  }
  __syncthreads();

  const int r0 = wv * RPW;
  float acc0[RPW], acc1[RPW];

  if (p < NCC){
    #pragma unroll
    for (int r = 0; r < RPW; r++){ acc0[r] = 0.f; acc1[r] = 0.f; }
    const float4* Wa4 = WTa + (size_t)p * 64 + lane;
    const float4* Wb4 = WTb + (size_t)p * 64 + lane;
    #pragma unroll 2
    for (int k4 = 0; k4 < K4; k4++){
      float4 w0 = Wa4[(size_t)k4 * C];
      float4 w1 = Wb4[(size_t)k4 * C];
      #pragma unroll
      for (int r = 0; r < RPW; r++){
        float4 xk = *(const float4*)&XS[r0 + r][k4 * 4];
        acc0[r] += xk.x * w0.x + xk.y * w0.y + xk.z * w0.z + xk.w * w0.w;
        acc1[r] += xk.x * w1.x + xk.y * w1.y + xk.z * w1.z + xk.w * w1.w;
      }
    }
    #pragma unroll
    for (int r = 0; r < RPW; r++){
      int row = rowbase + r0 + r;
      if (row < n){
        za[(size_t)row * C + p * 64 + lane] = acc0[r];
        zb[(size_t)row * C + p * 64 + lane] = acc1[r];
      }
    }
  } else if (lane < 2 * H){
    // ext: el/er from vvT (cols 0..2H-1)
    #pragma unroll
    for (int r = 0; r < RPW; r++) acc0[r] = 0.f;
    for (int k4 = 0; k4 < K4; k4++){
      float4 w0 = vvT[(size_t)k4 * (2 * H) + lane];
      #pragma unroll
      for (int r = 0; r < RPW; r++){
        float4 xk = *(const float4*)&XS[r0 + r][k4 * 4];
        acc0[r] += xk.x * w0.x + xk.y * w0.y + xk.z * w0.z + xk.w * w0.w;
      }
    }
    int h = lane >> 1;
    float* dst = (lane & 1) ? er : el;
    #pragma unroll
    for (int r = 0; r < RPW; r++){
      int row = rowbase + r0 + r;
      if (row < n) dst[(size_t)row * H + h] = acc0[r];
    }
  }
}

// ---------------- GAT 1-head, float4 gather, 2x slot-pairs in flight ----------------
// lane = slot q x float4-index j; 2*NS edges in flight per iteration (4 at D=128,
// 8 at D=64) -- halves the dependent L2-gather chain per node vs single-NS.
template<int D>
__global__ void k_gat_h1(const int* __restrict__ rowptr, const int* __restrict__ esrc,
                         const float* __restrict__ z, const float* __restrict__ el,
                         const float* __restrict__ er, const float* __restrict__ b,
                         const float* __restrict__ zb, const float* __restrict__ bb,
                         float* __restrict__ out, int n){
  constexpr int LPS = D / 4;
  constexpr int NS  = 64 / LPS;
  int lane = threadIdx.x & 63;
  int q = lane / LPS, j = lane % LPS;
  int i = blockIdx.x * (blockDim.x >> 6) + (threadIdx.x >> 6);
  if (i >= n) return;
  int s0 = rowptr[i], s1 = rowptr[i + 1];
  float eri = er[i];
  float m = -INFINITY;
  for (int e = s0 + lane; e < s1; e += 64)
    m = fmaxf(m, lrelu(el[esrc[e]] + eri));
  m = wred_max(m);
  float4 accA = make_float4(0.f, 0.f, 0.f, 0.f);
  float4 accB = make_float4(0.f, 0.f, 0.f, 0.f);
  float denA = 0.f, denB = 0.f;
  for (int base = s0; base < s1; base += 2 * NS){
    int e0 = base + q;
    int e1 = base + NS + q;
    bool ok0 = (e0 < s1), ok1 = (e1 < s1);
    int sA = esrc[ok0 ? e0 : s0];
    int sB = esrc[ok1 ? e1 : s0];
    float wA = ok0 ? __expf(lrelu(el[sA] + eri) - m) : 0.f;
    float wB = ok1 ? __expf(lrelu(el[sB] + eri) - m) : 0.f;
    denA += wA; denB += wB;
    float4 zA = *(const float4*)&z[(size_t)sA * D + 4 * j];
    float4 zB = *(const float4*)&z[(size_t)sB * D + 4 * j];
    accA.x += wA * zA.x; accA.y += wA * zA.y; accA.z += wA * zA.z; accA.w += wA * zA.w;
    accB.x += wB * zB.x; accB.y += wB * zB.y; accB.z += wB * zB.z; accB.w += wB * zB.w;
  }
  accA.x += accB.x; accA.y += accB.y; accA.z += accB.z; accA.w += accB.w;
  float den = denA + denB;
  #pragma unroll
  for (int o = LPS; o < 64; o <<= 1){
    accA.x += __shfl_xor(accA.x, o);
    accA.y += __shfl_xor(accA.y, o);
    accA.z += __shfl_xor(accA.z, o);
    accA.w += __shfl_xor(accA.w, o);
    den    += __shfl_xor(den, o);
  }
  float inv = (s1 > s0) ? 1.f / den : 0.f;
  if (lane < LPS){
    float4 bv  = *(const float4*)&b[4 * j];
    float4 ch  = *(const float4*)&bb[4 * j];
    if (i > 0){
      float4 zbv = *(const float4*)&zb[(size_t)(i - 1) * D + 4 * j];
      ch.x += zbv.x; ch.y += zbv.y; ch.z += zbv.z; ch.w += zbv.w;
    }
    float4 o4;
    o4.x = 0.5f * ((accA.x * inv + bv.x) + ch.x);
    o4.y = 0.5f * ((accA.y * inv + bv.y) + ch.y);
    o4.z = 0.5f * ((accA.z * inv + bv.z) + ch.z);
    o4.w = 0.5f * ((accA.w * inv + bv.w) + ch.w);
    *(float4*)&out[(size_t)i * D + 4 * j] = o4;
  }
}

// ---------------- GAT 4-head, float4 gather, 4 edges in flight ----------------
__global__ void k_gat_mh(const int* __restrict__ rowptr, const int* __restrict__ esrc,
                         const float* __restrict__ z, const float* __restrict__ el,
                         const float* __restrict__ er, const float* __restrict__ b,
                         const float* __restrict__ zb, const float* __restrict__ bb,
                         float* __restrict__ out, int n){
  int lane = threadIdx.x & 63;
  int h = lane >> 4;
  int i = blockIdx.x * (blockDim.x >> 6) + (threadIdx.x >> 6);
  if (i >= n) return;
  int s0 = rowptr[i], s1 = rowptr[i + 1];
  const float4 eri4 = *(const float4*)(er + (size_t)i * 4);
  float m0 = -INFINITY, m1 = -INFINITY, m2 = -INFINITY, m3 = -INFINITY;
  for (int e = s0 + lane; e < s1; e += 64){
    float4 e4 = *(const float4*)(el + (size_t)esrc[e] * 4);
    m0 = fmaxf(m0, lrelu(e4.x + eri4.x));
    m1 = fmaxf(m1, lrelu(e4.y + eri4.y));
    m2 = fmaxf(m2, lrelu(e4.z + eri4.z));
    m3 = fmaxf(m3, lrelu(e4.w + eri4.w));
  }
  m0 = wred_max(m0); m1 = wred_max(m1); m2 = wred_max(m2); m3 = wred_max(m3);
  float msel = (h & 2) ? ((h & 1) ? m3 : m2) : ((h & 1) ? m1 : m0);
  float erh  = sel4(h, eri4);

  float4 a0 = make_float4(0.f,0.f,0.f,0.f), a1 = a0, a2 = a0, a3 = a0;
  float d0 = 0.f, d1 = 0.f, d2 = 0.f, d3 = 0.f;
  int e = s0;
  for (; e + 3 < s1; e += 4){
    int sA = esrc[e], sB = esrc[e+1], sC = esrc[e+2], sD = esrc[e+3];
    float4 eA = *(const float4*)(el + (size_t)sA * 4);
    float4 eB = *(const float4*)(el + (size_t)sB * 4);
    float4 eC = *(const float4*)(el + (size_t)sC * 4);
    float4 eD = *(const float4*)(el + (size_t)sD * 4);
    float wA = __expf(lrelu(sel4(h, eA) + erh) - msel);
    float wB = __expf(lrelu(sel4(h, eB) + erh) - msel);
    float wC = __expf(lrelu(sel4(h, eC) + erh) - msel);
    float wD = __expf(lrelu(sel4(h, eD) + erh) - msel);
    d0 += wA; d1 += wB; d2 += wC; d3 += wD;
    float4 zA = *(const float4*)&z[(size_t)sA * 256 + 4 * lane];
    float4 zB = *(const float4*)&z[(size_t)sB * 256 + 4 * lane];
    float4 zC = *(const float4*)&z[(size_t)sC * 256 + 4 * lane];
    float4 zD = *(const float4*)&z[(size_t)sD * 256 + 4 * lane];
    a0.x += wA*zA.x; a0.y += wA*zA.y; a0.z += wA*zA.z; a0.w += wA*zA.w;
    a1.x += wB*zB.x; a1.y += wB*zB.y; a1.z += wB*zB.z; a1.w += wB*zB.w;
    a2.x += wC*zC.x; a2.y += wC*zC.y; a2.z += wC*zC.z; a2.w += wC*zC.w;
    a3.x += wD*zD.x; a3.y += wD*zD.y; a3.z += wD*zD.z; a3.w += wD*zD.w;
  }
  for (; e < s1; ++e){
    int sA = esrc[e];
    float4 eA = *(const float4*)(el + (size_t)sA * 4);
    float wA = __expf(lrelu(sel4(h, eA) + erh) - msel);
    d0 += wA;
    float4 zA = *(const float4*)&z[(size_t)sA * 256 + 4 * lane];
    a0.x += wA*zA.x; a0.y += wA*zA.y; a0.z += wA*zA.z; a0.w += wA*zA.w;
  }
  float den = d0 + d1 + d2 + d3;
  a0.x += a1.x + a2.x + a3.x;
  a0.y += a1.y + a2.y + a3.y;
  a0.z += a1.z + a2.z + a3.z;
  a0.w += a1.w + a2.w + a3.w;
  float inv = (s1 > s0) ? 1.f / den : 0.f;

  float4 bv = *(const float4*)&b[4 * lane];
  float4 ch = *(const float4*)&bb[4 * lane];
  if (i > 0){
    float4 zbv = *(const float4*)&zb[(size_t)(i - 1) * 256 + 4 * lane];
    ch.x += zbv.x; ch.y += zbv.y; ch.z += zbv.z; ch.w += zbv.w;
  }
  float4 o4;
  o4.x = 0.5f * ((a0.x * inv + bv.x) + ch.x);
  o4.y = 0.5f * ((a0.y * inv + bv.y) + ch.y);
  o4.z = 0.5f * ((a0.z * inv + bv.z) + ch.z);
  o4.w = 0.5f * ((a0.w * inv + bv.w) + ch.w);
  *(float4*)&out[(size_t)i * 256 + 4 * lane] = o4;
}

// ---------------- chain_pass ----------------
__global__ void k_chainpass64(const float* __restrict__ h, float* __restrict__ dh, int n){
  int lane = threadIdx.x & 63;
  int i = blockIdx.x * (blockDim.x >> 6) + (threadIdx.x >> 6);
  if (i >= n) return;
  float d = 0.f;
  if (i > 0) d = h[(size_t)(i - 1) * 64 + lane] - h[(size_t)i * 64 + lane];
  float ss = wred_sum(d * d);
  dh[(size_t)i * 64 + lane] = d / (sqrtf(ss) + 1e-7f);
}

__global__ void k_chainpass_mh(const float* __restrict__ hm, float* __restrict__ ds, int n){
  int lane = threadIdx.x & 63;
  int i = blockIdx.x * (blockDim.x >> 6) + (threadIdx.x >> 6);
  if (i >= n) return;
  const float* cur = hm + (size_t)i * 256;
  const float* prv = hm + (size_t)(i - 1) * 256;
  #pragma unroll
  for (int h = 0; h < 4; h++){
    int c = h * 64 + lane;
    float d = (i > 0) ? (prv[c] - cur[c]) : 0.f;
    float ss = wred_sum(d * d);
    ds[(size_t)i * 256 + c] = d / (sqrtf(ss) + 1e-7f);
  }
}

// ---------------- column-wise prefix sum over nodes (256 cols) ----------------
__global__ void k_chunk_sum(const float* __restrict__ ds, float* __restrict__ csum, int n, int ch){
  int b = blockIdx.x, t = threadIdx.x;
  int r0 = b * ch, r1 = r0 + ch; if (r1 > n) r1 = n;
  float s = 0.f;
  for (int r = r0; r < r1; r++) s += ds[(size_t)r * 256 + t];
  csum[(size_t)b * 256 + t] = s;
}
__global__ void k_scan_chunks_par(float* __restrict__ csum, int nb){
  __shared__ float s[512];
  int col = blockIdx.x;
  int t = threadIdx.x;
  s[t] = (t < nb) ? csum[(size_t)t * 256 + col] : 0.f;
  __syncthreads();
  #pragma unroll
  for (int o = 1; o < 512; o <<= 1){
    float add = (t >= o) ? s[t - o] : 0.f;
    __syncthreads();
    s[t] += add;
    __syncthreads();
  }
  if (t < nb) csum[(size_t)t * 256 + col] = (t > 0) ? s[t - 1] : 0.f;
}
__global__ void k_apply_scan(float* __restrict__ ds, const float* __restrict__ csum, int n, int ch){
  int b = blockIdx.x, t = threadIdx.x;
  int r0 = b * ch, r1 = r0 + ch; if (r1 > n) r1 = n;
  float run = csum[(size_t)b * 256 + t];
  for (int r = r0; r < r1; r++){
    run += ds[(size_t)r * 256 + t];
    ds[(size_t)r * 256 + t] = run;
  }
}

extern "C" void kernel_launch(void* const* d_in, const int* in_sizes, int n_in,
                              void* d_out, int out_size, void* d_ws, size_t ws_size,
                              hipStream_t stream){
  const float* x    = (const float*)d_in[0];
  const int*   src0 = (const int*)d_in[1];
  const int*   dst0 = (const int*)d_in[2];
  const float* W1a  = (const float*)d_in[5];
  const float* al1a = (const float*)d_in[6];
  const float* ar1a = (const float*)d_in[7];
  const float* b1a  = (const float*)d_in[8];
  const float* W1b  = (const float*)d_in[9];
  const float* b1b  = (const float*)d_in[12];
  const float* W2a  = (const float*)d_in[13];
  const float* al2a = (const float*)d_in[14];
  const float* ar2a = (const float*)d_in[15];
  const float* b2a  = (const float*)d_in[16];
  const float* W2b  = (const float*)d_in[17];
  const float* b2b  = (const float*)d_in[20];
  const float* Wma  = (const float*)d_in[21];
  const float* alma = (const float*)d_in[22];
  const float* arma = (const float*)d_in[23];
  const float* bma  = (const float*)d_in[24];
  const float* Wmb  = (const float*)d_in[25];
  const float* bmb  = (const float*)d_in[28];

  const int n = in_sizes[0] / 64;
  const int E = in_sizes[1];
  const size_t nf = (size_t)n;

  float* ws  = (float*)d_ws;
  float* A   = ws;
  float* B   = A + nf * 256;
  float* C   = B + nf * 256;
  float* D2  = C + nf * 256;   // h2 [n,64]
  float* E2  = D2 + nf * 64;   // dh [n,64]
  float* ela = E2 + nf * 64;   // [n,4]
  float* era = ela + nf * 4;
  const int ch = 100;
  const int nb = (n + ch - 1) / ch;      // 500 <= 512
  float* csum = era + nf * 4;  // [nb,256]
  float* wtbase = csum + (size_t)nb * 256;
  float4* T1a = (float4*)wtbase;          // [16][128] f4 = 2048
  float4* T1b = T1a + 2048;
  float4* T2a = T1b + 2048;               // [32][64]  f4 = 2048
  float4* T2b = T2a + 2048;
  float4* Tma = T2b + 2048;               // [16][256] f4 = 4096
  float4* Tmb = Tma + 4096;
  float* vvT1 = (float*)(Tmb + 4096);     // [16][2] f4 -> 128 floats
  float* vvT2 = vvT1 + 128;               // [32][2] f4 -> 256 floats
  float* vvTm = vvT2 + 256;               // [16][8] f4 -> 512 floats
  int* deg    = (int*)(vvTm + 512);
  int* rowptr = deg + n;
  int* cursor = rowptr + (n + 16);
  int* esrc   = cursor + n;
  int* bsum   = esrc + E;

  float* dsout = (float*)d_out;

  const int nwb  = (n + 3) / 4;
  const int eb   = (E + 255) / 256;
  const int nblk = (n + 255) / 256;

  // CSR of interacts graph by dst (shared by all three GAT layers)
  hipMemsetAsync(deg, 0, (size_t)n * sizeof(int), stream);
  k_hist<<<eb, 256, 0, stream>>>(dst0, deg, E);
  k_deg_bsum<<<nblk, 256, 0, stream>>>(deg, bsum, n);
  k_bsum_scan<<<1, 256, 0, stream>>>(bsum, nblk);
  k_rowptr<<<nblk, 256, 0, stream>>>(deg, bsum, rowptr, cursor, n, E);
  k_scatter<<<eb, 256, 0, stream>>>(src0, dst0, cursor, esrc, E);

  // weight preprocessing
  k_wtrans_all<<<64, 256, 0, stream>>>(W1a, W1b, W2a, W2b, Wma, Wmb,
                                       T1a, T1b, T2a, T2b, Tma, Tmb);
  k_valvar_all<<<3, 128, 0, stream>>>(W1a, al1a, ar1a, W2a, al2a, ar2a, Wma, alma, arma,
                                      vvT1, vvT2, vvTm);

  // layer 1: in=64 -> hid=128 (a+b fused; chunk-parallel grid.y = {0,1,ext})
  k_gemm2t<64, 128, 1><<<dim3((n + 63) / 64, 3), 256, 0, stream>>>(x, T1a, T1b, (const float4*)vvT1, A, B, ela, era, n);
  k_gat_h1<128><<<nwb, 256, 0, stream>>>(rowptr, esrc, A, ela, era, b1a, B, b1b, C, n);

  // layer 2: hid=128 -> out=64 (grid.y = {0,ext})
  k_gemm2t<128, 64, 1><<<dim3((n + 31) / 32, 2), 256, 0, stream>>>(C, T2a, T2b, (const float4*)vvT2, A, B, ela, era, n);
  k_gat_h1<64><<<nwb, 256, 0, stream>>>(rowptr, esrc, A, ela, era, b2a, B, b2b, D2, n);

  // dh = chain_pass(h2)
  k_chainpass64<<<nwb, 256, 0, stream>>>(D2, E2, n);

  // MH layer: out=64 -> 4 heads x 64 (grid.y = {0..3,ext})
  k_gemm2t<64, 256, 4><<<dim3((n + 63) / 64, 5), 256, 0, stream>>>(E2, Tma, Tmb, (const float4*)vvTm, A, B, ela, era, n);
  k_gat_mh<<<nwb, 256, 0, stream>>>(rowptr, esrc, A, ela, era, bma, B, bmb, C, n);

  // ds = chain_pass(hm) -> staged directly in d_out
  k_chainpass_mh<<<nwb, 256, 0, stream>>>(C, dsout, n);

  // res = cumsum(ds, axis=0), in-place in d_out
  k_chunk_sum<<<nb, 256, 0, stream>>>(dsout, csum, n, ch);
  k_scan_chunks_par<<<256, 512, 0, stream>>>(csum, nb);
  k_apply_scan<<<nb, 256, 0, stream>>>(dsout, csum, n, ch);
}